// Round 17
// baseline (82.344 us; speedup 1.0000x reference)
//
#include <hip/hip_runtime.h>
#include <math.h>
#include <stdint.h>

#define KK 5
#define PADK 2
#define C_IN 8
#define O_OUT 8
#define HH 512
#define WW 512
#define TH 8
#define TW 128
#define CH 4                      // channels per staged half
#define LROWS 12                  // TH + 4
#define LCOLS 136                 // TW + 4 halo, padded (f32 cols)
#define WSTR 12                   // dwords per (c,og,dy) chunk: 10 used
#define NW (O_OUT * C_IN * KK * KK)   // 1600
#define XHALF (CH * LROWS * (LCOLS / 2))   // float2 slots per half = 3264
#define NSTG 7                    // ceil(XHALF / 512)
#define XPAD (NSTG * 512)         // padded float2 slots = 3584

// Full-rate VOP3 3-input max.
static __device__ __forceinline__ float max3f(float a, float b, float c) {
    float d;
    asm("v_max3_f32 %0, %1, %2, %3" : "=v"(d) : "v"(a), "v"(b), "v"(c));
    return d;
}

__global__ __launch_bounds__(512, 8)
void dil_kernel(const float* __restrict__ x,
                const float* __restrict__ wf,
                float* __restrict__ out) {
    // xlds padded to XPAD float2 slots so staging writes are unconditional.
    __shared__ __align__(16) float xlds[2 * XPAD];              // 28,672 B
    __shared__ __align__(16) float wlds[C_IN * 4 * KK * WSTR];  //  7,680 B

    const int tid = threadIdx.x;
    const int w0 = blockIdx.x * TW;
    const int h0 = blockIdx.y * TH;
    const int n  = blockIdx.z;
    const float* xn = x + (size_t)n * (C_IN * HH * WW);

    const int l   = tid & 63;
    const int wid = tid >> 6;
    const int og  = wid & 3;
    const int rbase = (wid >> 2) * 4;

    // registers holding in-flight staging loads (no branches -> stay in VGPRs)
    float2 stg[NSTG];

// issue NSTG clamped, unconditional global loads for half hh
#define STAGE_L(hh)                                                        \
    _Pragma("unroll")                                                      \
    for (int k = 0; k < NSTG; ++k) {                                       \
        int idx = tid + k * 512;                                           \
        int ci  = min(idx, XHALF - 1);                                     \
        int cc  = ci / (LROWS * (LCOLS / 2));                              \
        int rem = ci - cc * (LROWS * (LCOLS / 2));                         \
        int r   = rem / (LCOLS / 2);                                       \
        int jp  = rem - r * (LCOLS / 2);                                   \
        int gh  = min(max(h0 - PADK + r, 0), HH - 1);                      \
        int gw  = min(max(w0 - PADK + 2 * jp, 0), WW - 2);                 \
        stg[k] = *(const float2*)(                                         \
            xn + ((size_t)((hh) * CH + cc) * HH + gh) * WW + gw);          \
    }

// apply halo zero-mask and write all NSTG regs to (padded) LDS
#define STAGE_W()                                                          \
    _Pragma("unroll")                                                      \
    for (int k = 0; k < NSTG; ++k) {                                       \
        int idx = tid + k * 512;                                           \
        int ci  = min(idx, XHALF - 1);                                     \
        int cc  = ci / (LROWS * (LCOLS / 2));                              \
        int rem = ci - cc * (LROWS * (LCOLS / 2));                         \
        int r   = rem / (LCOLS / 2);                                       \
        int jp  = rem - r * (LCOLS / 2);                                   \
        int gh  = h0 - PADK + r;                                           \
        int gw  = w0 - PADK + 2 * jp;                                      \
        bool ok = ((unsigned)gh < (unsigned)HH) &                          \
                  ((unsigned)gw < (unsigned)WW) & (idx < XHALF);           \
        float2 v;                                                          \
        v.x = ok ? stg[k].x : 0.f;                                         \
        v.y = ok ? stg[k].y : 0.f;                                         \
        *(float2*)(&xlds[2 * idx]) = v;                                    \
    }

    float acc[2][4][2];
    #pragma unroll
    for (int a = 0; a < 2; ++a)
        #pragma unroll
        for (int j = 0; j < 4; ++j) {
            acc[a][j][0] = -INFINITY;
            acc[a][j][1] = -INFINITY;
        }

    const float* xbase = &xlds[rbase * LCOLS + 2 * l];
    const float* wog   = wlds + og * (KK * WSTR);

// compute over the 4 channels currently in xlds (weight half hh)
#define COMPUTE(hh)                                                        \
    _Pragma("unroll")                                                      \
    for (int cc = 0; cc < CH; ++cc) {                                      \
        _Pragma("unroll")                                                  \
        for (int dy = 0; dy < KK; ++dy) {                                  \
            const float* wch = wog + ((hh) * CH * 4 * KK                   \
                                      + cc * 4 * KK + dy) * WSTR;          \
            float4 wa = *(const float4*)(wch);                             \
            float4 wv = *(const float4*)(wch + 4);                         \
            float2 wc2 = *(const float2*)(wch + 8);                        \
            const float w[10] = {wa.x, wa.y, wa.z, wa.w,                   \
                                 wv.x, wv.y, wv.z, wv.w, wc2.x, wc2.y};    \
            _Pragma("unroll")                                              \
            for (int j = 0; j < 4; ++j) {                                  \
                const float* lr = xbase + cc * (LROWS * LCOLS)             \
                                        + (dy + j) * LCOLS;                \
                float2 A = *(const float2*)(lr);                           \
                float2 B = *(const float2*)(lr + 2);                       \
                float2 D = *(const float2*)(lr + 4);                       \
                const float u0 = A.x, u1 = A.y, u2 = B.x,                  \
                            u3 = B.y, u4 = D.x, u5 = D.y;                  \
                _Pragma("unroll")                                          \
                for (int o2 = 0; o2 < 2; ++o2) {                           \
                    const float* wo = &w[o2 * 5];                          \
                    float t0 = u0 + wo[0], t1 = u1 + wo[1],                \
                          t2 = u2 + wo[2], t3 = u3 + wo[3],                \
                          t4 = u4 + wo[4];                                 \
                    acc[o2][j][0] = max3f(acc[o2][j][0],                   \
                                          max3f(t0, t1, t2),               \
                                          fmaxf(t3, t4));                  \
                    float s0 = u1 + wo[0], s1 = u2 + wo[1],                \
                          s2 = u3 + wo[2], s3 = u4 + wo[3],                \
                          s4 = u5 + wo[4];                                 \
                    acc[o2][j][1] = max3f(acc[o2][j][1],                   \
                                          max3f(s0, s1, s2),               \
                                          fmaxf(s3, s4));                  \
                }                                                          \
            }                                                              \
        }                                                                  \
    }

    // ---- prologue: load half 0 + weights, write, barrier ----
    STAGE_L(0)
    for (int t = tid; t < NW; t += 512) {
        int dx = t % KK;  int q = t / KK;
        int o2 = q & 1;   q >>= 1;
        int dy = q % KK;  q /= KK;
        int g  = q & 3;   int c = q >> 2;
        int o = g * 2 + o2;
        wlds[((c * 4 + g) * KK + dy) * WSTR + o2 * KK + dx] =
            wf[((o * C_IN + c) * KK + dy) * KK + dx];
    }
    STAGE_W()
    __syncthreads();

    // ---- half-1 loads issued BEFORE compute(0): HBM latency hidden ----
    STAGE_L(1)
    COMPUTE(0)
    __syncthreads();
    STAGE_W()
    __syncthreads();
    COMPUTE(1)

#undef STAGE_L
#undef STAGE_W
#undef COMPUTE

    // ---- store: 2 consecutive pixels -> one float2, coalesced ----
    float* onp = out + (size_t)n * (O_OUT * HH * WW);
    const int hB = h0 + rbase;
    const int wcol = w0 + 2 * l;
    float* obase = &onp[((size_t)(og * 2) * HH + hB) * WW + wcol];
    #pragma unroll
    for (int o2 = 0; o2 < 2; ++o2) {
        #pragma unroll
        for (int j = 0; j < 4; ++j) {
            float2 rr = make_float2(acc[o2][j][0], acc[o2][j][1]);
            *(float2*)(obase + (size_t)o2 * (HH * WW) + j * WW) = rr;
        }
    }
}

extern "C" void kernel_launch(void* const* d_in, const int* in_sizes, int n_in,
                              void* d_out, int out_size, void* d_ws, size_t ws_size,
                              hipStream_t stream) {
    const float* x   = (const float*)d_in[0];
    const float* wgt = (const float*)d_in[1];
    float* out = (float*)d_out;

    dim3 grid(WW / TW, HH / TH, 4);   // (4, 64, 4) = 1024 blocks x 512 thr
    dim3 block(512);
    dil_kernel<<<grid, block, 0, stream>>>(x, wgt, out);
}